// Round 3
// baseline (2387.165 us; speedup 1.0000x reference)
//
#include <hip/hip_runtime.h>
#include <stdint.h>

typedef uint16_t u16;
typedef unsigned long long u64;
typedef __attribute__((ext_vector_type(8))) short short8;   // 8 x bf16 bits (4 VGPRs)
typedef __attribute__((ext_vector_type(4))) float f32x4;

#define SCOPE __HIP_MEMORY_SCOPE_AGENT
#define FSTRIDE 16   // ints per edge flag line (64B): 4 per-wave flags
#define FLD(p) __hip_atomic_load((p), __ATOMIC_RELAXED, SCOPE)
#define FST(p, v) __hip_atomic_store((p), (v), __ATOMIC_RELAXED, SCOPE)

template <int N> struct IC { static constexpr int value = N; };

static __device__ __forceinline__ float bf2f(u16 b) {
  union { uint32_t u; float f; } x; x.u = ((uint32_t)b) << 16; return x.f;
}
static __device__ __forceinline__ u16 f2bf(float f) {
  union { float f; uint32_t u; } x; x.f = f;
  uint32_t u = x.u;
  u += 0x7fffu + ((u >> 16) & 1u);   // RTNE
  return (u16)(u >> 16);
}
// inf-safe: exp(+inf)->inf, 1+inf=inf, rcp(inf)=0; exp(-inf)->0.
static __device__ __forceinline__ float sigm(float x) {
  return __builtin_amdgcn_rcpf(1.f + __expf(-x));
}
static __device__ __forceinline__ float tanhf_(float x) {
  return 1.f - 2.f * __builtin_amdgcn_rcpf(1.f + __expf(2.f * x));
}
// LDS-only barrier: does NOT drain vmcnt.
static __device__ __forceinline__ void lds_barrier() {
  asm volatile("s_waitcnt lgkmcnt(0)\n\ts_barrier" ::: "memory");
}
#define DRAIN0() asm volatile("s_waitcnt vmcnt(0)" ::: "memory")
static __device__ __forceinline__ int imin(int a, int b) { return a < b ? a : b; }

// R12: weights OUT of the register file, into LDS (MFMA-fragment tile layout).
// Diagnosis of R9-R11's protocol-invariant ~4us/step floor: weight register
// demand is 64 short8 = 256 VGPR before accs/staging (NKCA and P==31 are
// runtime -> compiler can't shrink) => allocator pegged at the 256 ceiling
// (VGPR_Count=256 every round) => per-step AGPR/scratch shuffling of weights
// (~1-2k extra ops/step), matching the anomalous VALUBusy. R11's verified
// plane-split ring + relaxed chunk protocol kept unchanged.
// LDS tile layout: tile(nt,kc) of row-major W (N x K): lane l holds
// W[nt*16 + (l&15)][kc*32 + (l>>4)*8 + j], 16B at tilebase + l*16 -> one
// conflict-free ds_read_b128 per B-fragment, kc folds into the offset imm.
// Budget: WhhA/WhhB/WihB 24KB each + WihA 48KB (K=128 worst; P31 aliases
// upper half for Wo) = 120KB dynamic + 32.25KB static = ~155KB < 160KB.
// MFMA 16x16x32 bf16 layouts (m89-verified):
//   A-frag: lane holds A[m=lane&15][k=(lane>>4)*8+j]
//   B-frag: lane holds B[k=(lane>>4)*8+j][n=lane&15]  (W row-major (N,K))
//   C/D: reg p -> (row=(lane>>4)*4+p, col=lane&15)
#define OFF_WHA 0
#define OFF_WHB 12288
#define OFF_WIB 24576
#define OFF_WIA 36864
#define OFF_WO  49152
#define DYN_U16 61440   // 122880 bytes

template <int CHE, int CHD>
__global__ __launch_bounds__(256, 1) void gru_pipeline(
    const void* ctx_,
    const void* eWih0_, const void* eWih_, const void* eWhh_,
    const void* ebih_,  const void* ebhh_,
    const void* dWih0_, const void* dWih_, const void* dWhh_,
    const void* dbih_,  const void* dbhh_,
    const void* Wo_,    const void* bo_,   void* out_,
    int* __restrict__ pflag, int* __restrict__ cflag,
    u64* __restrict__ xbufW, int RW, int RE)
{
  const int tid  = threadIdx.x;
  const int lane = tid & 63;
  const int wid  = tid >> 6;
  const int rt   = wid >> 1;      // row-tile (16 batch rows each)
  const int cs   = wid & 1;       // gate-col half
  const int lo   = lane & 15;
  const int hi   = lane >> 4;
  const int blk  = blockIdx.x;
  const int P    = blk >> 2;      // layer pair 0..31  (layers 2P, 2P+1)
  const int g    = blk & 3;       // batch chunk
  const int LA   = 2 * P;
  const int LB   = 2 * P + 1;
  const int NKCA = (P == 0) ? 4 : 2;   // layer A k-chunks (K=128 for layer 0)
  u64* xbufE = (u64*)out_;             // encoder-phase ring lives in d_out

  extern __shared__ __align__(16) u16 dynlds[];   // weight tiles (120KB)

  __shared__ __align__(16) u16 hbA[2][32 * 72];
  __shared__ __align__(16) u16 hbB[2][32 * 72];
  __shared__ __align__(16) u16 xstA[2][32 * 72];
  __shared__ __align__(16) u16 xstB[32 * 72];
  __shared__ int s_cnt, s_fin, s_cn;
  if (tid == 0) { s_cnt = 0; s_fin = 0; s_cn = 0; }
  for (int i = tid; i < 32 * 72; i += 256) {
    hbA[0][i] = 0; hbA[1][i] = 0; hbB[0][i] = 0; hbB[1][i] = 0;
    xstA[0][i] = 0; xstA[1][i] = 0; xstB[i] = 0;
  }
  __syncthreads();
  {  // dtype probe: even u16s of enc_bih
    u16 v = ((const u16*)ebih_)[2 * tid];
    int e = (v >> 7) & 0xFF;
    if (e >= 100 && e <= 126) atomicAdd(&s_cnt, 1);
  }
  __syncthreads();
  const bool bf = (s_cnt >= 128);   // true: bf16 tensors; false: fp32

  auto ld8 = [&](const void* p, int idx) -> short8 {
    if (bf) return *(const short8*)((const u16*)p + idx);
    const float* f = (const float*)p + idx;
    short8 r;
#pragma unroll
    for (int j = 0; j < 8; ++j) r[j] = (short)f2bf(f[j]);
    return r;
  };
  auto ld1 = [&](const void* p, int idx) -> float {
    return bf ? bf2f(((const u16*)p)[idx]) : ((const float*)p)[idx];
  };

  int T[6];
  T[0] = 2*cs; T[1] = 2*cs+1; T[2] = 4+2*cs; T[3] = 5+2*cs; T[4] = 8+2*cs; T[5] = 9+2*cs;

  short8 zf8 = {0,0,0,0,0,0,0,0};
  float  bov[2] = {0.f, 0.f};
  float brzA[4], binA[2], bhnA[2];
  float brzB[4], binB[2], bhnB[2];

  // ---- cooperative stage of a row-major (NT*16 x KC*32) matrix into LDS tiles
  auto stage_w = [&](int offU16, const void* W, int gidx0, int NT, int KC, int K) {
    for (int nt = wid; nt < NT; nt += 4)
      for (int kc = 0; kc < KC; ++kc) {
        short8 v = ld8(W, gidx0 + (nt*16 + lo)*K + kc*32 + hi*8);
        *(short8*)(dynlds + offU16 + (nt*KC + kc)*512 + lane*8) = v;
      }
  };

  auto load_phase = [&](int ph) {
    const void* WH  = ph ? dWhh_ : eWhh_;
    const void* WIs = ph ? dWih_ : eWih_;
    const void* WI0 = ph ? dWih0_ : eWih0_;
    const void* bi  = ph ? dbih_ : ebih_;
    const void* bh  = ph ? dbhh_ : ebhh_;
    stage_w(OFF_WHA, WH, LA*192*64, 12, 2, 64);
    stage_w(OFF_WHB, WH, LB*192*64, 12, 2, 64);
    stage_w(OFF_WIB, WIs, LA*192*64, 12, 2, 64);   // Wih[LB-1] = Wih[LA]
    if (LA == 0) stage_w(OFF_WIA, WI0, 0, 12, 4, 128);
    else         stage_w(OFF_WIA, WIs, (LA-1)*192*64, 12, 2, 64);
#pragma unroll
    for (int q = 0; q < 4; ++q) {
      brzA[q] = ld1(bi, LA*192 + T[q]*16 + lo) + ld1(bh, LA*192 + T[q]*16 + lo);
      brzB[q] = ld1(bi, LB*192 + T[q]*16 + lo) + ld1(bh, LB*192 + T[q]*16 + lo);
    }
#pragma unroll
    for (int q = 0; q < 2; ++q) {
      binA[q] = ld1(bi, LA*192 + T[4+q]*16 + lo);
      bhnA[q] = ld1(bh, LA*192 + T[4+q]*16 + lo);
      binB[q] = ld1(bi, LB*192 + T[4+q]*16 + lo);
      bhnB[q] = ld1(bh, LB*192 + T[4+q]*16 + lo);
    }
  };
  load_phase(0);
  if (P == 31) {   // Wo staged once: OFF_WO region untouched by load_phase(1) (KCA=2)
    stage_w(OFF_WO, Wo_, 0, 8, 2, 64);
#pragma unroll
    for (int ct = 0; ct < 2; ++ct) bov[ct] = ld1(bo_, 32*wid + 16*ct + lo);
  }

  // ---- precomputed LDS byte... u16 offsets for weight fragments
  int oWhA[6], oWhB[6], oWiB[6], oWiA[6];
#pragma unroll
  for (int ti = 0; ti < 6; ++ti) {
    oWhA[ti] = OFF_WHA + T[ti]*1024 + lane*8;
    oWhB[ti] = OFF_WHB + T[ti]*1024 + lane*8;
    oWiB[ti] = OFF_WIB + T[ti]*1024 + lane*8;
    oWiA[ti] = OFF_WIA + T[ti]*(NKCA*512) + lane*8;
  }
  const int oWo0 = OFF_WO + (2*wid + 0)*1024 + lane*8;
  const int oWo1 = OFF_WO + (2*wid + 1)*1024 + lane*8;

  auto WF = [&](int off, int kc) -> short8 {   // one ds_read_b128, kc folds to imm
    return *(const short8*)(dynlds + off + kc*512);
  };

  auto do_proj = [&](int tprev, const u16* hs) {
    f32x4 pacc[2][2];
#pragma unroll
    for (int rtl = 0; rtl < 2; ++rtl)
#pragma unroll
      for (int ct = 0; ct < 2; ++ct) {
        float v = bov[ct]; f32x4 tv = {v, v, v, v}; pacc[rtl][ct] = tv;
      }
#pragma unroll
    for (int kc = 0; kc < 2; ++kc) {
      short8 hA0 = *(const short8*)(hs + (0*16 + lo)*72 + kc*32 + hi*8);
      short8 hA1 = *(const short8*)(hs + (1*16 + lo)*72 + kc*32 + hi*8);
      short8 w0 = WF(oWo0, kc), w1 = WF(oWo1, kc);
      pacc[0][0] = __builtin_amdgcn_mfma_f32_16x16x32_bf16(hA0, w0, pacc[0][0], 0, 0, 0);
      pacc[0][1] = __builtin_amdgcn_mfma_f32_16x16x32_bf16(hA0, w1, pacc[0][1], 0, 0, 0);
      pacc[1][0] = __builtin_amdgcn_mfma_f32_16x16x32_bf16(hA1, w0, pacc[1][0], 0, 0, 0);
      pacc[1][1] = __builtin_amdgcn_mfma_f32_16x16x32_bf16(hA1, w1, pacc[1][1], 0, 0, 0);
    }
#pragma unroll
    for (int rtl = 0; rtl < 2; ++rtl)
#pragma unroll
      for (int ct = 0; ct < 2; ++ct) {
        int n = 32*wid + 16*ct + lo;
#pragma unroll
        for (int p = 0; p < 4; ++p) {
          int b = 32*g + rtl*16 + hi*4 + p;
          size_t idx = ((size_t)b * 256 + (tprev - 256)) * 128 + n;
          float v = fminf(64.f, fmaxf(-64.f, pacc[rtl][ct][p]));
          if (bf) ((u16*)out_)[idx] = f2bf(v);
          else    ((float*)out_)[idx] = v;
        }
      }
  };

  float hprevA[2][4], hprevB[2][4];
#pragma unroll
  for (int q = 0; q < 2; ++q)
#pragma unroll
    for (int p = 0; p < 4; ++p) { hprevA[q][p] = 0.f; hprevB[q][p] = 0.f; }

  const int brow = 32*g + rt*16 + lo;

  const int eIn  = (P > 0 ? P - 1 : 0) * 4 + g;   // deref'd only when P>0
  const int eOut = (P < 31 ? P : 30) * 4 + g;     // deref'd only when P<31
  int* fin   = pflag + eIn  * FSTRIDE;            // 4 per-wave producer flags
  int* fout  = pflag + eOut * FSTRIDE;
  int* cself = cflag + (P * 4 + g) * FSTRIDE;     // 4 per-wave consumer credits
  int* cnext = cflag + ((P < 31 ? P + 1 : 31) * 4 + g) * FSTRIDE;

  int budget = 1 << 22;   // anti-hang
  const int srow = (tid >> 7) * 16 + ((tid >> 4) & 3) * 4;
  const int scol = ((tid >> 6) & 1) * 32 + (tid & 15);

  int f0 = 0, f1 = 0, f2 = 0, f3 = 0;       // tid0 flag probes (issued 1 step early)
  int c0 = 0, c1 = 0, c2 = 0, c3 = 0;       // tid0 credit probes

  __syncthreads();   // weight tiles + buffers visible

  // ---------------- chunked span: CH steps per chunk, fully unrolled ----------------
  auto span = [&](auto chc, const int tbase, const int cbase, const int RC, const bool dec) {
    constexpr int CH  = decltype(chc)::value;
    constexpr int PTT = (CH >= 2) ? CH - 2 : 0;   // probe-issue step
    const int NC   = 256 / CH;
    const int RM   = dec ? (RW - 1) : (RE - 1);
    const int toff = dec ? 256 : 0;
    const u64* rbi = dec ? (xbufW + (size_t)eIn  * ((size_t)RW * 512))
                         : (xbufE + (size_t)eIn  * ((size_t)RE * 512));
    u64*       rbo = dec ? (xbufW + (size_t)eOut * ((size_t)RW * 512))
                         : (xbufE + (size_t)eOut * ((size_t)RE * 512));

#pragma unroll 1
    for (int k = 0; k < NC; ++k) {
      const int ck    = cbase + k;
      const int t0    = tbase + k * CH;
      const int fneed = ck + 1;
      const int need  = (k >= RC) ? (cbase + k + 1 - RC) : 0;

      // ---- slow path only when pipelined probes say we're not ready (rare)
      const bool slowF = (P > 0)  && (s_fin < fneed);
      const bool slowC = (P < 31) && (need > 0) && (s_cn < need);
      if (slowF || slowC) {
        if (tid == 0) {
          if (slowF) {
            int v = 0;
            while (budget > 0) {
              int a = FLD(fin + 0), b = FLD(fin + 1), c = FLD(fin + 2), d = FLD(fin + 3);
              v = imin(imin(a, b), imin(c, d));
              if (v >= fneed) break;
              --budget; __builtin_amdgcn_s_sleep(2);
            }
            s_fin = v;
          }
          if (slowC) {
            int v = 0;
            while (budget > 0) {
              int a = FLD(cnext + 0), b = FLD(cnext + 1), c = FLD(cnext + 2), d = FLD(cnext + 3);
              v = imin(imin(a, b), imin(c, d));
              if (v >= need) break;
              --budget; __builtin_amdgcn_s_sleep(2);
            }
            s_cn = v;
          }
        }
        lds_barrier();
      }

      // ---- prime the whole chunk's records (static regs; plane-split full lines)
      u64 pa[CH], pb[CH];
#pragma unroll
      for (int j = 0; j < CH; ++j) { pa[j] = 0; pb[j] = 0; }
      if (P > 0) {
#pragma unroll
        for (int j = 0; j < CH; ++j) {
          const u64* rj = rbi + (size_t)((t0 + j - toff) & RM) * 512;
          pa[j] = FLD(rj + tid);
          pb[j] = FLD(rj + 256 + tid);
        }
      }

#pragma unroll
      for (int tt = 0; tt < CH; ++tt) {
        const int t = t0 + tt;

        // ---- stage x_t for layer A -> xstA[t&1]
        if (P > 0) {
          u16* xd = xstA[t & 1];
#pragma unroll
          for (int p = 0; p < 4; ++p) {
            xd[(srow + p) * 72 + scol]      = (u16)(pa[tt] >> (16 * p));
            xd[(srow + p) * 72 + scol + 16] = (u16)(pb[tt] >> (16 * p));
          }
        }

        lds_barrier();   // B1: xstA(t), hbA(t-1), hbB(t-1) visible

        // ---- probe issue (1 step before publish; latency hidden under compute)
        if (tt == PTT && tid == 0) {
          if (P > 0)  { f0 = FLD(fin + 0); f1 = FLD(fin + 1); f2 = FLD(fin + 2); f3 = FLD(fin + 3); }
          if (P < 31) { c0 = FLD(cnext + 0); c1 = FLD(cnext + 1); c2 = FLD(cnext + 2); c3 = FLD(cnext + 3); }
        }

        // ---- pair 31: projection of step t-1 (h63_{t-1} in hbB[(t+1)&1])
        if (P == 31 && t >= 257) do_proj(t - 1, hbB[(t + 1) & 1]);

        // ================= layer A =================
        f32x4 acc_rz[4], acc_in[2], acc_hn[2];
#pragma unroll
        for (int q = 0; q < 4; ++q) { float v = brzA[q]; f32x4 tv = {v,v,v,v}; acc_rz[q] = tv; }
#pragma unroll
        for (int q = 0; q < 2; ++q) { float v = binA[q]; f32x4 tv = {v,v,v,v}; acc_in[q] = tv;
                                      float w = bhnA[q]; f32x4 tw = {w,w,w,w}; acc_hn[q] = tw; }
        const u16* hsA = hbA[(t + 1) & 1];
#pragma unroll
        for (int kc = 0; kc < 2; ++kc) {
          short8 hA = *(const short8*)(hsA + (rt*16 + lo)*72 + kc*32 + hi*8);
          short8 w0 = WF(oWhA[0], kc), w1 = WF(oWhA[1], kc), w2 = WF(oWhA[2], kc);
          short8 w3 = WF(oWhA[3], kc), w4 = WF(oWhA[4], kc), w5 = WF(oWhA[5], kc);
          acc_rz[0] = __builtin_amdgcn_mfma_f32_16x16x32_bf16(hA, w0, acc_rz[0], 0, 0, 0);
          acc_rz[1] = __builtin_amdgcn_mfma_f32_16x16x32_bf16(hA, w1, acc_rz[1], 0, 0, 0);
          acc_rz[2] = __builtin_amdgcn_mfma_f32_16x16x32_bf16(hA, w2, acc_rz[2], 0, 0, 0);
          acc_rz[3] = __builtin_amdgcn_mfma_f32_16x16x32_bf16(hA, w3, acc_rz[3], 0, 0, 0);
          acc_hn[0] = __builtin_amdgcn_mfma_f32_16x16x32_bf16(hA, w4, acc_hn[0], 0, 0, 0);
          acc_hn[1] = __builtin_amdgcn_mfma_f32_16x16x32_bf16(hA, w5, acc_hn[1], 0, 0, 0);
        }
        short8 xfA[4] = {zf8, zf8, zf8, zf8};
        if (P > 0) {
          const u16* xs = xstA[t & 1];
#pragma unroll
          for (int kc = 0; kc < 2; ++kc)
            xfA[kc] = *(const short8*)(xs + (rt*16 + lo)*72 + kc*32 + hi*8);
        } else {
          int tx = (t < 256) ? t : ((t == 256) ? 0 : t - 257);
#pragma unroll
          for (int kc = 0; kc < 4; ++kc)
            xfA[kc] = ld8(ctx_, (brow * 256 + tx) * 128 + kc*32 + hi*8);
        }
        if (!(P == 0 && t == 256)) {
#pragma unroll
          for (int kc = 0; kc < 4; ++kc) {
            if (kc < NKCA) {
              short8 w0 = WF(oWiA[0], kc), w1 = WF(oWiA[1], kc), w2 = WF(oWiA[2], kc);
              short8 w3 = WF(oWiA[3], kc), w4 = WF(oWiA[4], kc), w5 = WF(oWiA[5], kc);
              acc_rz[0] = __builtin_amdgcn_mfma_f32_16x16x32_bf16(xfA[kc], w0, acc_rz[0], 0, 0, 0);
              acc_rz[1] = __builtin_amdgcn_mfma_f32_16x16x32_bf16(xfA[kc], w1, acc_rz[1], 0, 0, 0);
              acc_rz[2] = __builtin_amdgcn_mfma_f32_16x16x32_bf16(xfA[kc], w2, acc_rz[2], 0, 0, 0);
              acc_rz[3] = __builtin_amdgcn_mfma_f32_16x16x32_bf16(xfA[kc], w3, acc_rz[3], 0, 0, 0);
              acc_in[0] = __builtin_amdgcn_mfma_f32_16x16x32_bf16(xfA[kc], w4, acc_in[0], 0, 0, 0);
              acc_in[1] = __builtin_amdgcn_mfma_f32_16x16x32_bf16(xfA[kc], w5, acc_in[1], 0, 0, 0);
            }
          }
        }
        u16 hAb[2][4];
#pragma unroll
        for (int q = 0; q < 2; ++q)
#pragma unroll
          for (int p = 0; p < 4; ++p) {
            float r = sigm(acc_rz[q][p]);
            float z = sigm(acc_rz[2 + q][p]);
            float n = tanhf_(acc_in[q][p] + r * acc_hn[q][p]);
            float h = n + z * (hprevA[q][p] - n);
            h = fminf(1.f, fmaxf(-1.f, h));
            hprevA[q][p] = h;
            hAb[q][p] = f2bf(h);
          }

        // ---- probe publish (pre-B2 so next chunk's readers are ordered)
        if (tt == CH - 1 && tid == 0) {
          if (P > 0)  s_fin = imin(imin(f0, f1), imin(f2, f3));
          if (P < 31) s_cn  = imin(imin(c0, c1), imin(c2, c3));
        }

        {  // h_A -> hbA[t&1] (recurrence) and xstB (x for layer B)
          u16* hd = hbA[t & 1];
#pragma unroll
          for (int q = 0; q < 2; ++q)
#pragma unroll
            for (int p = 0; p < 4; ++p) {
              int ridx = (rt*16 + hi*4 + p) * 72 + cs*32 + q*16 + lo;
              hd[ridx] = hAb[q][p];
              xstB[ridx] = hAb[q][p];
            }
        }

        lds_barrier();   // B2: xstB(t) visible

        // ================= layer B =================
#pragma unroll
        for (int q = 0; q < 4; ++q) { float v = brzB[q]; f32x4 tv = {v,v,v,v}; acc_rz[q] = tv; }
#pragma unroll
        for (int q = 0; q < 2; ++q) { float v = binB[q]; f32x4 tv = {v,v,v,v}; acc_in[q] = tv;
                                      float w = bhnB[q]; f32x4 tw = {w,w,w,w}; acc_hn[q] = tw; }
        const u16* hsB = hbB[(t + 1) & 1];
#pragma unroll
        for (int kc = 0; kc < 2; ++kc) {
          short8 hB = *(const short8*)(hsB + (rt*16 + lo)*72 + kc*32 + hi*8);
          short8 xB = *(const short8*)(xstB + (rt*16 + lo)*72 + kc*32 + hi*8);
          short8 u0 = WF(oWhB[0], kc), u1 = WF(oWhB[1], kc), u2 = WF(oWhB[2], kc);
          short8 u3 = WF(oWhB[3], kc), u4 = WF(oWhB[4], kc), u5 = WF(oWhB[5], kc);
          acc_rz[0] = __builtin_amdgcn_mfma_f32_16x16x32_bf16(hB, u0, acc_rz[0], 0, 0, 0);
          acc_rz[1] = __builtin_amdgcn_mfma_f32_16x16x32_bf16(hB, u1, acc_rz[1], 0, 0, 0);
          acc_rz[2] = __builtin_amdgcn_mfma_f32_16x16x32_bf16(hB, u2, acc_rz[2], 0, 0, 0);
          acc_rz[3] = __builtin_amdgcn_mfma_f32_16x16x32_bf16(hB, u3, acc_rz[3], 0, 0, 0);
          acc_hn[0] = __builtin_amdgcn_mfma_f32_16x16x32_bf16(hB, u4, acc_hn[0], 0, 0, 0);
          acc_hn[1] = __builtin_amdgcn_mfma_f32_16x16x32_bf16(hB, u5, acc_hn[1], 0, 0, 0);
          short8 v0 = WF(oWiB[0], kc), v1 = WF(oWiB[1], kc), v2 = WF(oWiB[2], kc);
          short8 v3 = WF(oWiB[3], kc), v4 = WF(oWiB[4], kc), v5 = WF(oWiB[5], kc);
          acc_rz[0] = __builtin_amdgcn_mfma_f32_16x16x32_bf16(xB, v0, acc_rz[0], 0, 0, 0);
          acc_rz[1] = __builtin_amdgcn_mfma_f32_16x16x32_bf16(xB, v1, acc_rz[1], 0, 0, 0);
          acc_rz[2] = __builtin_amdgcn_mfma_f32_16x16x32_bf16(xB, v2, acc_rz[2], 0, 0, 0);
          acc_rz[3] = __builtin_amdgcn_mfma_f32_16x16x32_bf16(xB, v3, acc_rz[3], 0, 0, 0);
          acc_in[0] = __builtin_amdgcn_mfma_f32_16x16x32_bf16(xB, v4, acc_in[0], 0, 0, 0);
          acc_in[1] = __builtin_amdgcn_mfma_f32_16x16x32_bf16(xB, v5, acc_in[1], 0, 0, 0);
        }
        u16 hBb[2][4];
#pragma unroll
        for (int q = 0; q < 2; ++q)
#pragma unroll
          for (int p = 0; p < 4; ++p) {
            float r = sigm(acc_rz[q][p]);
            float z = sigm(acc_rz[2 + q][p]);
            float n = tanhf_(acc_in[q][p] + r * acc_hn[q][p]);
            float h = n + z * (hprevB[q][p] - n);
            h = fminf(1.f, fmaxf(-1.f, h));
            hprevB[q][p] = h;
            hBb[q][p] = f2bf(h);
          }
        {
          u16* hd = hbB[t & 1];
#pragma unroll
          for (int q = 0; q < 2; ++q)
#pragma unroll
            for (int p = 0; p < 4; ++p)
              hd[(rt*16 + hi*4 + p) * 72 + cs*32 + q*16 + lo] = hBb[q][p];
        }
        if (P < 31) {   // record h_B for the next pair (plane-split: full lines)
          u64 da = (u64)hBb[0][0] | ((u64)hBb[0][1] << 16) | ((u64)hBb[0][2] << 32) | ((u64)hBb[0][3] << 48);
          u64 db = (u64)hBb[1][0] | ((u64)hBb[1][1] << 16) | ((u64)hBb[1][2] << 32) | ((u64)hBb[1][3] << 48);
          u64* ro = rbo + (size_t)((t - toff) & RM) * 512;
          FST(ro + tid, da);
          FST(ro + 256 + tid, db);
        }
      }

      // ---- chunk end: per-wave drain + flag/credit (no __syncthreads)
      if (P < 31) {
        DRAIN0();                                   // wave's ring stores at MALL
        if (lane == 0) FST(fout + wid, ck + 1);
      }
      if (P > 0 && lane == 0) FST(cself + wid, ck + 1);  // wave's prime loads retired
    }
  };

  span(IC<CHE>{}, 0, 0, RE / CHE, false);        // encoder: ring in d_out
  __syncthreads();   // all waves done reading encoder weight tiles
  load_phase(1);     // rewrite LDS weight tiles for decoder phase
  __syncthreads();   // decoder tiles visible
  {
    int rcd = RW / CHD; if (rcd < 1) rcd = 1;
    span(IC<CHD>{}, 256, 256 / CHE, rcd, true);  // decoder: ring in workspace
  }

  // ---- epilogue: projection of the final step (t = 511)
  lds_barrier();
  if (P == 31) do_proj(511, hbB[1]);
}

extern "C" void kernel_launch(void* const* d_in, const int* in_sizes, int n_in,
                              void* d_out, int out_size, void* d_ws, size_t ws_size,
                              hipStream_t stream)
{
  char* ws = (char*)d_ws;
  int* pflag = (int*)ws;                    // 124 edges x 64B per-wave flag lines
  int* cflag = (int*)(ws + 8192);           // 128 x 64B per-wave credit lines
  u64* xbufW = (u64*)(ws + 16384);          // decoder-phase handoff ring

  const size_t per_slot = (size_t)31 * 4 * 4096;  // one ring step across all 31x4 edges
  size_t avail = (ws_size > 16384) ? ws_size - 16384 : 0;
  int RW = 1;
  for (int r = 128; r >= 1; r >>= 1)
    if ((size_t)r * per_slot <= avail) { RW = r; break; }
  // encoder-phase ring borrows d_out (dead until pair31's first projection)
  int RE = 1;
  for (int r = 16; r >= 1; r >>= 1)
    if ((size_t)r * per_slot <= (size_t)out_size) { RE = r; break; }

  const int dyn = 122880;   // 120KB weight tiles in dynamic LDS
  static int attr_done = 0;
  if (!attr_done) {
    hipFuncSetAttribute(reinterpret_cast<const void*>(gru_pipeline<4,4>),
                        hipFuncAttributeMaxDynamicSharedMemorySize, dyn);
    hipFuncSetAttribute(reinterpret_cast<const void*>(gru_pipeline<4,2>),
                        hipFuncAttributeMaxDynamicSharedMemorySize, dyn);
    hipFuncSetAttribute(reinterpret_cast<const void*>(gru_pipeline<4,1>),
                        hipFuncAttributeMaxDynamicSharedMemorySize, dyn);
    hipFuncSetAttribute(reinterpret_cast<const void*>(gru_pipeline<1,1>),
                        hipFuncAttributeMaxDynamicSharedMemorySize, dyn);
    attr_done = 1;
  }

  hipMemsetAsync(ws, 0, 16384, stream);     // zero flags every launch

#define LAUNCH(CE, CD)                                                     \
  gru_pipeline<CE, CD><<<128, 256, dyn, stream>>>(                         \
      d_in[0], d_in[1], d_in[2], d_in[3], d_in[4], d_in[5],                \
      d_in[6], d_in[7], d_in[8], d_in[9], d_in[10], d_in[11], d_in[12],    \
      d_out, pflag, cflag, xbufW, RW, RE)

  if (RE >= 4) {
    if      (RW >= 8) LAUNCH(4, 4);
    else if (RW >= 4) LAUNCH(4, 2);
    else              LAUNCH(4, 1);
  } else {
    LAUNCH(1, 1);
  }
#undef LAUNCH
  (void)in_sizes; (void)n_in;
}

// Round 4
// 1769.106 us; speedup vs baseline: 1.3494x; 1.3494x over previous
//
#include <hip/hip_runtime.h>
#include <stdint.h>

typedef uint16_t u16;
typedef unsigned long long u64;
typedef __attribute__((ext_vector_type(8))) short short8;   // 8 x bf16 bits (4 VGPRs)
typedef __attribute__((ext_vector_type(4))) float f32x4;

#define SCOPE __HIP_MEMORY_SCOPE_AGENT
#define FSTRIDE 16   // ints per edge flag line (64B): 4 per-wave flags
#define FLD(p) __hip_atomic_load((p), __ATOMIC_RELAXED, SCOPE)
#define FST(p, v) __hip_atomic_store((p), (v), __ATOMIC_RELAXED, SCOPE)

template <int N> struct IC { static constexpr int value = N; };

static __device__ __forceinline__ float bf2f(u16 b) {
  union { uint32_t u; float f; } x; x.u = ((uint32_t)b) << 16; return x.f;
}
static __device__ __forceinline__ u16 f2bf(float f) {
  union { float f; uint32_t u; } x; x.f = f;
  uint32_t u = x.u;
  u += 0x7fffu + ((u >> 16) & 1u);   // RTNE
  return (u16)(u >> 16);
}
// inf-safe: exp(+inf)->inf, 1+inf=inf, rcp(inf)=0; exp(-inf)->0.
static __device__ __forceinline__ float sigm(float x) {
  return __builtin_amdgcn_rcpf(1.f + __expf(-x));
}
static __device__ __forceinline__ float tanhf_(float x) {
  return 1.f - 2.f * __builtin_amdgcn_rcpf(1.f + __expf(2.f * x));
}
// LDS-only barrier: does NOT drain vmcnt.
static __device__ __forceinline__ void lds_barrier() {
  asm volatile("s_waitcnt lgkmcnt(0)\n\ts_barrier" ::: "memory");
}
#define DRAIN0() asm volatile("s_waitcnt vmcnt(0)" ::: "memory")
static __device__ __forceinline__ int imin(int a, int b) { return a < b ? a : b; }

// R13: batch split 4->8: 256 WGs (ALL CUs), 16 rows/WG, wave = gate-quarter.
// Post-mortem R12: VGPR 256->140 (theory signature hit) but dur flat AND +36
// ds_read/step was free -> per-step period is NOT instruction-bound. R9-R12
// all ~2.3-2.7ms across 3 protocols => wall = exposed latency, 1 wave/SIMD on
// half the CUs (active-CU VALUBusy 20% @ 11k cyc/step = IPC 0.2, serialized).
// Fix: double CUs (grid 256) + halve per-wave chain (24 MFMA/step, 4 outs/thr).
// Chunk protocol / rings / flags / LDS-weights kept IDENTICAL to R12.
// Record = 1 u64/thread: index (col*4 + rowquad), full lines both directions.
// MFMA 16x16x32 bf16 layouts (m89-verified):
//   A-frag: lane holds A[m=lane&15][k=(lane>>4)*8+j]
//   B-frag: lane holds B[k=(lane>>4)*8+j][n=lane&15]  (W row-major (N,K))
//   C/D: reg p -> (row=(lane>>4)*4+p, col=lane&15)
#define OFF_WHA 0
#define OFF_WHB 12288
#define OFF_WIB 24576
#define OFF_WIA 36864
#define OFF_WO  49152

template <int CHE, int CHD>
__global__ __launch_bounds__(256, 1) void gru_pipeline(
    const void* ctx_,
    const void* eWih0_, const void* eWih_, const void* eWhh_,
    const void* ebih_,  const void* ebhh_,
    const void* dWih0_, const void* dWih_, const void* dWhh_,
    const void* dbih_,  const void* dbhh_,
    const void* Wo_,    const void* bo_,   void* out_,
    int* __restrict__ pflag, int* __restrict__ cflag,
    u64* __restrict__ xbufW, int RW, int RE)
{
  const int tid  = threadIdx.x;
  const int lane = tid & 63;
  const int q    = tid >> 6;      // gate-quarter wave: tiles {q, 4+q, 8+q}
  const int lo   = lane & 15;
  const int hi   = lane >> 4;
  const int blk  = blockIdx.x;
  const int P    = blk >> 3;      // layer pair 0..31  (layers 2P, 2P+1)
  const int g    = blk & 7;       // batch chunk (16 rows)
  const int LA   = 2 * P;
  const int LB   = 2 * P + 1;
  const int NKCA = (P == 0) ? 4 : 2;   // layer A k-chunks (K=128 for layer 0)
  u64* xbufE = (u64*)out_;             // encoder-phase ring lives in d_out

  extern __shared__ __align__(16) u16 dynlds[];   // weight tiles (120KB)

  __shared__ __align__(16) u16 hbA[2][16 * 72];
  __shared__ __align__(16) u16 hbB[2][16 * 72];
  __shared__ __align__(16) u16 xstA[2][16 * 72];
  __shared__ int s_cnt, s_fin, s_cn;
  if (tid == 0) { s_cnt = 0; s_fin = 0; s_cn = 0; }
  for (int i = tid; i < 16 * 72; i += 256) {
    hbA[0][i] = 0; hbA[1][i] = 0; hbB[0][i] = 0; hbB[1][i] = 0;
    xstA[0][i] = 0; xstA[1][i] = 0;
  }
  __syncthreads();
  {  // dtype probe: even u16s of enc_bih
    u16 v = ((const u16*)ebih_)[2 * tid];
    int e = (v >> 7) & 0xFF;
    if (e >= 100 && e <= 126) atomicAdd(&s_cnt, 1);
  }
  __syncthreads();
  const bool bf = (s_cnt >= 128);   // true: bf16 tensors; false: fp32

  auto ld8 = [&](const void* p, int idx) -> short8 {
    if (bf) return *(const short8*)((const u16*)p + idx);
    const float* f = (const float*)p + idx;
    short8 r;
#pragma unroll
    for (int j = 0; j < 8; ++j) r[j] = (short)f2bf(f[j]);
    return r;
  };
  auto ld1 = [&](const void* p, int idx) -> float {
    return bf ? bf2f(((const u16*)p)[idx]) : ((const float*)p)[idx];
  };

  const int T0 = q, T1 = 4 + q, T2 = 8 + q;

  short8 zf8 = {0,0,0,0,0,0,0,0};
  float  bov[2] = {0.f, 0.f};
  float brzA[2], binA, bhnA;
  float brzB[2], binB, bhnB;

  // ---- cooperative stage of a row-major (NT*16 x KC*32) matrix into LDS tiles
  auto stage_w = [&](int offU16, const void* W, int gidx0, int NT, int KC, int K) {
    for (int nt = q; nt < NT; nt += 4)
      for (int kc = 0; kc < KC; ++kc) {
        short8 v = ld8(W, gidx0 + (nt*16 + lo)*K + kc*32 + hi*8);
        *(short8*)(dynlds + offU16 + (nt*KC + kc)*512 + lane*8) = v;
      }
  };

  auto load_phase = [&](int ph) {
    const void* WH  = ph ? dWhh_ : eWhh_;
    const void* WIs = ph ? dWih_ : eWih_;
    const void* WI0 = ph ? dWih0_ : eWih0_;
    const void* bi  = ph ? dbih_ : ebih_;
    const void* bh  = ph ? dbhh_ : ebhh_;
    stage_w(OFF_WHA, WH, LA*192*64, 12, 2, 64);
    stage_w(OFF_WHB, WH, LB*192*64, 12, 2, 64);
    stage_w(OFF_WIB, WIs, LA*192*64, 12, 2, 64);   // Wih[LB-1] = Wih[LA]
    if (LA == 0) stage_w(OFF_WIA, WI0, 0, 12, 4, 128);
    else         stage_w(OFF_WIA, WIs, (LA-1)*192*64, 12, 2, 64);
    brzA[0] = ld1(bi, LA*192 + T0*16 + lo) + ld1(bh, LA*192 + T0*16 + lo);
    brzA[1] = ld1(bi, LA*192 + T1*16 + lo) + ld1(bh, LA*192 + T1*16 + lo);
    binA    = ld1(bi, LA*192 + T2*16 + lo);
    bhnA    = ld1(bh, LA*192 + T2*16 + lo);
    brzB[0] = ld1(bi, LB*192 + T0*16 + lo) + ld1(bh, LB*192 + T0*16 + lo);
    brzB[1] = ld1(bi, LB*192 + T1*16 + lo) + ld1(bh, LB*192 + T1*16 + lo);
    binB    = ld1(bi, LB*192 + T2*16 + lo);
    bhnB    = ld1(bh, LB*192 + T2*16 + lo);
  };
  load_phase(0);
  if (P == 31) {   // Wo staged once (OFF_WO untouched by load_phase(1): KCA=2)
    stage_w(OFF_WO, Wo_, 0, 8, 2, 64);
    bov[0] = ld1(bo_, 32*q + lo);
    bov[1] = ld1(bo_, 32*q + 16 + lo);
  }

  // ---- precomputed LDS u16 offsets for weight fragments
  const int oWhA0 = OFF_WHA + T0*1024 + lane*8;
  const int oWhA1 = OFF_WHA + T1*1024 + lane*8;
  const int oWhA2 = OFF_WHA + T2*1024 + lane*8;
  const int oWhB0 = OFF_WHB + T0*1024 + lane*8;
  const int oWhB1 = OFF_WHB + T1*1024 + lane*8;
  const int oWhB2 = OFF_WHB + T2*1024 + lane*8;
  const int oWiB0 = OFF_WIB + T0*1024 + lane*8;
  const int oWiB1 = OFF_WIB + T1*1024 + lane*8;
  const int oWiB2 = OFF_WIB + T2*1024 + lane*8;
  const int oWiA0 = OFF_WIA + T0*(NKCA*512) + lane*8;
  const int oWiA1 = OFF_WIA + T1*(NKCA*512) + lane*8;
  const int oWiA2 = OFF_WIA + T2*(NKCA*512) + lane*8;
  const int oWo0  = OFF_WO + (2*q + 0)*1024 + lane*8;
  const int oWo1  = OFF_WO + (2*q + 1)*1024 + lane*8;

  auto WF = [&](int off, int kc) -> short8 {   // one ds_read_b128, kc -> imm
    return *(const short8*)(dynlds + off + kc*512);
  };

  auto do_proj = [&](int tprev, const u16* hs) {
    f32x4 pacc[2];
#pragma unroll
    for (int ct = 0; ct < 2; ++ct) { float v = bov[ct]; f32x4 tv = {v,v,v,v}; pacc[ct] = tv; }
#pragma unroll
    for (int kc = 0; kc < 2; ++kc) {
      short8 hA = *(const short8*)(hs + lo*72 + kc*32 + hi*8);
      pacc[0] = __builtin_amdgcn_mfma_f32_16x16x32_bf16(hA, WF(oWo0, kc), pacc[0], 0, 0, 0);
      pacc[1] = __builtin_amdgcn_mfma_f32_16x16x32_bf16(hA, WF(oWo1, kc), pacc[1], 0, 0, 0);
    }
#pragma unroll
    for (int ct = 0; ct < 2; ++ct) {
      int n = 32*q + 16*ct + lo;
#pragma unroll
      for (int p = 0; p < 4; ++p) {
        int b = 16*g + hi*4 + p;
        size_t idx = ((size_t)b * 256 + (tprev - 256)) * 128 + n;
        float v = fminf(64.f, fmaxf(-64.f, pacc[ct][p]));
        if (bf) ((u16*)out_)[idx] = f2bf(v);
        else    ((float*)out_)[idx] = v;
      }
    }
  };

  float hprevA[4], hprevB[4];
#pragma unroll
  for (int p = 0; p < 4; ++p) { hprevA[p] = 0.f; hprevB[p] = 0.f; }

  const int brow = 16*g + lo;   // P0 context row

  const int eIn  = (P > 0 ? P - 1 : 0) * 8 + g;   // deref'd only when P>0
  const int eOut = (P < 31 ? P : 30) * 8 + g;     // deref'd only when P<31
  int* fin   = pflag + eIn  * FSTRIDE;            // 4 per-wave producer flags
  int* fout  = pflag + eOut * FSTRIDE;
  int* cself = cflag + (P * 8 + g) * FSTRIDE;     // 4 per-wave consumer credits
  int* cnext = cflag + ((P < 31 ? P + 1 : 31) * 8 + g) * FSTRIDE;

  int budget = 1 << 22;   // anti-hang
  const int srow = 4 * (tid & 3);   // record unpack: row quad
  const int scol = tid >> 2;        // record unpack: h column

  int f0 = 0, f1 = 0, f2 = 0, f3 = 0;   // tid0 flag probes (issued 1 step early)
  int c0 = 0, c1 = 0, c2 = 0, c3 = 0;   // tid0 credit probes

  __syncthreads();   // weight tiles + buffers visible

  // ---------------- chunked span: CH steps per chunk, fully unrolled ----------------
  auto span = [&](auto chc, const int tbase, const int cbase, const int RC, const bool dec) {
    constexpr int CH  = decltype(chc)::value;
    constexpr int PTT = (CH >= 2) ? CH - 2 : 0;   // probe-issue step
    const int NC   = 256 / CH;
    const int RM   = dec ? (RW - 1) : (RE - 1);
    const int toff = dec ? 256 : 0;
    const u64* rbi = dec ? (xbufW + (size_t)eIn  * ((size_t)RW * 256))
                         : (xbufE + (size_t)eIn  * ((size_t)RE * 256));
    u64*       rbo = dec ? (xbufW + (size_t)eOut * ((size_t)RW * 256))
                         : (xbufE + (size_t)eOut * ((size_t)RE * 256));

#pragma unroll 1
    for (int k = 0; k < NC; ++k) {
      const int ck    = cbase + k;
      const int t0    = tbase + k * CH;
      const int fneed = ck + 1;
      const int need  = (k >= RC) ? (cbase + k + 1 - RC) : 0;

      // ---- slow path only when pipelined probes say we're not ready
      const bool slowF = (P > 0)  && (s_fin < fneed);
      const bool slowC = (P < 31) && (need > 0) && (s_cn < need);
      if (slowF || slowC) {
        if (tid == 0) {
          if (slowF) {
            int v = 0;
            while (budget > 0) {
              int a = FLD(fin + 0), b = FLD(fin + 1), c = FLD(fin + 2), d = FLD(fin + 3);
              v = imin(imin(a, b), imin(c, d));
              if (v >= fneed) break;
              --budget; __builtin_amdgcn_s_sleep(2);
            }
            s_fin = v;
          }
          if (slowC) {
            int v = 0;
            while (budget > 0) {
              int a = FLD(cnext + 0), b = FLD(cnext + 1), c = FLD(cnext + 2), d = FLD(cnext + 3);
              v = imin(imin(a, b), imin(c, d));
              if (v >= need) break;
              --budget; __builtin_amdgcn_s_sleep(2);
            }
            s_cn = v;
          }
        }
        lds_barrier();
      }

      // ---- prime the whole chunk's records (1 u64/thread/step, full lines)
      u64 pa[CH];
#pragma unroll
      for (int j = 0; j < CH; ++j) pa[j] = 0;
      if (P > 0) {
#pragma unroll
        for (int j = 0; j < CH; ++j)
          pa[j] = FLD(rbi + (size_t)((t0 + j - toff) & RM) * 256 + tid);
      }

#pragma unroll
      for (int tt = 0; tt < CH; ++tt) {
        const int t = t0 + tt;

        // ---- stage x_t for layer A -> xstA[t&1]
        if (P > 0) {
          u16* xd = xstA[t & 1];
#pragma unroll
          for (int p = 0; p < 4; ++p)
            xd[(srow + p) * 72 + scol] = (u16)(pa[tt] >> (16 * p));
        }

        lds_barrier();   // B1: xstA(t), hbA(t-1), hbB(t-1) visible

        // ---- probe issue (1 step before publish; latency hidden under compute)
        if (tt == PTT && tid == 0) {
          if (P > 0)  { f0 = FLD(fin + 0); f1 = FLD(fin + 1); f2 = FLD(fin + 2); f3 = FLD(fin + 3); }
          if (P < 31) { c0 = FLD(cnext + 0); c1 = FLD(cnext + 1); c2 = FLD(cnext + 2); c3 = FLD(cnext + 3); }
        }

        // ---- pair 31: projection of step t-1 (h63_{t-1} in hbB[(t+1)&1])
        if (P == 31 && t >= 257) do_proj(t - 1, hbB[(t + 1) & 1]);

        // ================= layer A =================
        f32x4 ar, az, ain, ahn;
        { float v;
          v = brzA[0]; ar  = (f32x4){v,v,v,v};
          v = brzA[1]; az  = (f32x4){v,v,v,v};
          v = binA;    ain = (f32x4){v,v,v,v};
          v = bhnA;    ahn = (f32x4){v,v,v,v}; }
        const u16* hsA = hbA[(t + 1) & 1];
#pragma unroll
        for (int kc = 0; kc < 2; ++kc) {
          short8 hA = *(const short8*)(hsA + lo*72 + kc*32 + hi*8);
          ar  = __builtin_amdgcn_mfma_f32_16x16x32_bf16(hA, WF(oWhA0, kc), ar,  0, 0, 0);
          az  = __builtin_amdgcn_mfma_f32_16x16x32_bf16(hA, WF(oWhA1, kc), az,  0, 0, 0);
          ahn = __builtin_amdgcn_mfma_f32_16x16x32_bf16(hA, WF(oWhA2, kc), ahn, 0, 0, 0);
        }
        short8 xfA[4] = {zf8, zf8, zf8, zf8};
        if (P > 0) {
          const u16* xs = xstA[t & 1];
#pragma unroll
          for (int kc = 0; kc < 2; ++kc)
            xfA[kc] = *(const short8*)(xs + lo*72 + kc*32 + hi*8);
        } else {
          int tx = (t < 256) ? t : ((t == 256) ? 0 : t - 257);
#pragma unroll
          for (int kc = 0; kc < 4; ++kc)
            xfA[kc] = ld8(ctx_, (brow * 256 + tx) * 128 + kc*32 + hi*8);
        }
        if (!(P == 0 && t == 256)) {
#pragma unroll
          for (int kc = 0; kc < 4; ++kc) {
            if (kc < NKCA) {
              ar  = __builtin_amdgcn_mfma_f32_16x16x32_bf16(xfA[kc], WF(oWiA0, kc), ar,  0, 0, 0);
              az  = __builtin_amdgcn_mfma_f32_16x16x32_bf16(xfA[kc], WF(oWiA1, kc), az,  0, 0, 0);
              ain = __builtin_amdgcn_mfma_f32_16x16x32_bf16(xfA[kc], WF(oWiA2, kc), ain, 0, 0, 0);
            }
          }
        }
        u16 hAb[4];
#pragma unroll
        for (int p = 0; p < 4; ++p) {
          float r = sigm(ar[p]);
          float z = sigm(az[p]);
          float n = tanhf_(ain[p] + r * ahn[p]);
          float h = n + z * (hprevA[p] - n);
          h = fminf(1.f, fmaxf(-1.f, h));
          hprevA[p] = h;
          hAb[p] = f2bf(h);
        }

        // ---- probe publish (pre-B2 so next chunk's readers are ordered)
        if (tt == CH - 1 && tid == 0) {
          if (P > 0)  s_fin = imin(imin(f0, f1), imin(f2, f3));
          if (P < 31) s_cn  = imin(imin(c0, c1), imin(c2, c3));
        }

        {  // h_A -> hbA[t&1] (recurrence + layer-B input; wave q owns cols 16q..)
          u16* hd = hbA[t & 1];
#pragma unroll
          for (int p = 0; p < 4; ++p)
            hd[(hi*4 + p) * 72 + q*16 + lo] = hAb[p];
        }

        lds_barrier();   // B2: hbA(t) visible

        // ================= layer B =================
        { float v;
          v = brzB[0]; ar  = (f32x4){v,v,v,v};
          v = brzB[1]; az  = (f32x4){v,v,v,v};
          v = binB;    ain = (f32x4){v,v,v,v};
          v = bhnB;    ahn = (f32x4){v,v,v,v}; }
        const u16* hsB = hbB[(t + 1) & 1];
        const u16* xsB = hbA[t & 1];
#pragma unroll
        for (int kc = 0; kc < 2; ++kc) {
          short8 hB = *(const short8*)(hsB + lo*72 + kc*32 + hi*8);
          short8 xB = *(const short8*)(xsB + lo*72 + kc*32 + hi*8);
          ar  = __builtin_amdgcn_mfma_f32_16x16x32_bf16(hB, WF(oWhB0, kc), ar,  0, 0, 0);
          az  = __builtin_amdgcn_mfma_f32_16x16x32_bf16(hB, WF(oWhB1, kc), az,  0, 0, 0);
          ahn = __builtin_amdgcn_mfma_f32_16x16x32_bf16(hB, WF(oWhB2, kc), ahn, 0, 0, 0);
          ar  = __builtin_amdgcn_mfma_f32_16x16x32_bf16(xB, WF(oWiB0, kc), ar,  0, 0, 0);
          az  = __builtin_amdgcn_mfma_f32_16x16x32_bf16(xB, WF(oWiB1, kc), az,  0, 0, 0);
          ain = __builtin_amdgcn_mfma_f32_16x16x32_bf16(xB, WF(oWiB2, kc), ain, 0, 0, 0);
        }
        u16 hBb[4];
#pragma unroll
        for (int p = 0; p < 4; ++p) {
          float r = sigm(ar[p]);
          float z = sigm(az[p]);
          float n = tanhf_(ain[p] + r * ahn[p]);
          float h = n + z * (hprevB[p] - n);
          h = fminf(1.f, fmaxf(-1.f, h));
          hprevB[p] = h;
          hBb[p] = f2bf(h);
        }
        {
          u16* hd = hbB[t & 1];
#pragma unroll
          for (int p = 0; p < 4; ++p)
            hd[(hi*4 + p) * 72 + q*16 + lo] = hBb[p];
        }
        if (P < 31) {   // record h_B: u64 packs 4 rows at col 16q+lo
          u64 da = (u64)hBb[0] | ((u64)hBb[1] << 16) | ((u64)hBb[2] << 32) | ((u64)hBb[3] << 48);
          FST(rbo + (size_t)((t - toff) & RM) * 256 + (16*q + lo)*4 + hi, da);
        }
      }

      // ---- chunk end: per-wave drain + flag/credit (no __syncthreads)
      if (P < 31) {
        DRAIN0();                                  // wave's ring stores at MALL
        if (lane == 0) FST(fout + q, ck + 1);
      }
      if (P > 0 && lane == 0) FST(cself + q, ck + 1);  // prime loads retired
    }
  };

  span(IC<CHE>{}, 0, 0, RE / CHE, false);        // encoder: ring in d_out
  __syncthreads();   // all waves done reading encoder weight tiles
  load_phase(1);     // rewrite LDS weight tiles for decoder phase
  __syncthreads();   // decoder tiles visible
  {
    int rcd = RW / CHD; if (rcd < 1) rcd = 1;
    span(IC<CHD>{}, 256, 256 / CHE, rcd, true);  // decoder: ring in workspace
  }

  // ---- epilogue: projection of the final step (t = 511)
  lds_barrier();
  if (P == 31) do_proj(511, hbB[1]);
}

extern "C" void kernel_launch(void* const* d_in, const int* in_sizes, int n_in,
                              void* d_out, int out_size, void* d_ws, size_t ws_size,
                              hipStream_t stream)
{
  char* ws = (char*)d_ws;
  int* pflag = (int*)ws;                    // 248 edges x 64B per-wave flag lines
  int* cflag = (int*)(ws + 16384);          // 256 x 64B per-wave credit lines
  u64* xbufW = (u64*)(ws + 32768);          // decoder-phase handoff ring

  const size_t per_slot = (size_t)31 * 8 * 2048;  // one ring step across all 31x8 edges
  size_t avail = (ws_size > 32768) ? ws_size - 32768 : 0;
  int RW = 1;
  for (int r = 128; r >= 1; r >>= 1)
    if ((size_t)r * per_slot <= avail) { RW = r; break; }
  // encoder-phase ring borrows d_out (dead until pair31's first projection)
  int RE = 1;
  for (int r = 16; r >= 1; r >>= 1)
    if ((size_t)r * per_slot <= (size_t)out_size) { RE = r; break; }

  const int dyn = 122880;   // 120KB weight tiles in dynamic LDS
  static int attr_done = 0;
  if (!attr_done) {
    hipFuncSetAttribute(reinterpret_cast<const void*>(gru_pipeline<4,4>),
                        hipFuncAttributeMaxDynamicSharedMemorySize, dyn);
    hipFuncSetAttribute(reinterpret_cast<const void*>(gru_pipeline<4,2>),
                        hipFuncAttributeMaxDynamicSharedMemorySize, dyn);
    hipFuncSetAttribute(reinterpret_cast<const void*>(gru_pipeline<4,1>),
                        hipFuncAttributeMaxDynamicSharedMemorySize, dyn);
    hipFuncSetAttribute(reinterpret_cast<const void*>(gru_pipeline<1,1>),
                        hipFuncAttributeMaxDynamicSharedMemorySize, dyn);
    attr_done = 1;
  }

  hipMemsetAsync(ws, 0, 32768, stream);     // zero flags every launch

#define LAUNCH(CE, CD)                                                     \
  gru_pipeline<CE, CD><<<256, 256, dyn, stream>>>(                         \
      d_in[0], d_in[1], d_in[2], d_in[3], d_in[4], d_in[5],                \
      d_in[6], d_in[7], d_in[8], d_in[9], d_in[10], d_in[11], d_in[12],    \
      d_out, pflag, cflag, xbufW, RW, RE)

  if (RE >= 4) {
    if      (RW >= 8) LAUNCH(4, 4);
    else if (RW >= 4) LAUNCH(4, 2);
    else              LAUNCH(4, 1);
  } else {
    LAUNCH(1, 1);
  }
#undef LAUNCH
  (void)in_sizes; (void)n_in;
}

// Round 5
// 1708.428 us; speedup vs baseline: 1.3973x; 1.0355x over previous
//
#include <hip/hip_runtime.h>
#include <stdint.h>

typedef uint16_t u16;
typedef unsigned long long u64;
typedef __attribute__((ext_vector_type(8))) short short8;   // 8 x bf16 bits (4 VGPRs)
typedef __attribute__((ext_vector_type(4))) float f32x4;

#define SCOPE __HIP_MEMORY_SCOPE_AGENT
#define FSTRIDE 16   // ints per edge flag line (64B): 4 per-wave flags
#define FLD(p) __hip_atomic_load((p), __ATOMIC_RELAXED, SCOPE)
#define FST(p, v) __hip_atomic_store((p), (v), __ATOMIC_RELAXED, SCOPE)

template <int N> struct IC { static constexpr int value = N; };

static __device__ __forceinline__ float bf2f(u16 b) {
  union { uint32_t u; float f; } x; x.u = ((uint32_t)b) << 16; return x.f;
}
static __device__ __forceinline__ u16 f2bf(float f) {
  union { float f; uint32_t u; } x; x.f = f;
  uint32_t u = x.u;
  u += 0x7fffu + ((u >> 16) & 1u);   // RTNE
  return (u16)(u >> 16);
}
// inf-safe: exp(+inf)->inf, 1+inf=inf, rcp(inf)=0; exp(-inf)->0.
static __device__ __forceinline__ float sigm(float x) {
  return __builtin_amdgcn_rcpf(1.f + __expf(-x));
}
static __device__ __forceinline__ float tanhf_(float x) {
  return 1.f - 2.f * __builtin_amdgcn_rcpf(1.f + __expf(2.f * x));
}
// LDS-only barrier: does NOT drain vmcnt.
static __device__ __forceinline__ void lds_barrier() {
  asm volatile("s_waitcnt lgkmcnt(0)\n\ts_barrier" ::: "memory");
}
#define DRAIN0() asm volatile("s_waitcnt vmcnt(0)" ::: "memory")
static __device__ __forceinline__ int imin(int a, int b) { return a < b ? a : b; }

// R14: intra-WG layer pipelining -> 2 waves/SIMD. 512 thr/WG: X-group (waves
// 0-3) computes layer A of step t while Y-group (waves 4-7) computes layer B of
// step t-1; ONE lds_barrier per slot. Post-mortem R13: occupancy doubled as
// predicted (5.7->10.7%) and dur -26% -- parallelism IS the wall; but still
// 1 wave/SIMD (IPC~0.2, all latency exposed). This doubles waves/SIMD with
// independent streams and halves each wave's serial chain (12 MFMA + 4-elem
// act/slot). Protocol kept (chunked relaxed flags/credits, plane-split ring);
// skew-forced deltas: stage x(t+1) at slot t (prime window [t0+1,t0+CH],
// fneed=ck+2); producer flag for chunk c released after first slot of chunk
// c+1 (last record stores one slot late); CHE=2 so encoder credit window
// [2, RE/CHE=8] has slack. P0 prefetches ctx one slot ahead (pipeline head).
// MFMA 16x16x32 bf16 layouts (m89-verified):
//   A-frag: lane holds A[m=lane&15][k=(lane>>4)*8+j]
//   B-frag: lane holds B[k=(lane>>4)*8+j][n=lane&15]  (W row-major (N,K))
//   C/D: reg p -> (row=(lane>>4)*4+p, col=lane&15)
#define OFF_WHA 0
#define OFF_WHB 12288
#define OFF_WIB 24576
#define OFF_WIA 36864
#define OFF_WO  49152

template <int CHE, int CHD>
__global__ __launch_bounds__(512, 1) void gru_pipeline(
    const void* ctx_,
    const void* eWih0_, const void* eWih_, const void* eWhh_,
    const void* ebih_,  const void* ebhh_,
    const void* dWih0_, const void* dWih_, const void* dWhh_,
    const void* dbih_,  const void* dbhh_,
    const void* Wo_,    const void* bo_,   void* out_,
    int* __restrict__ pflag, int* __restrict__ cflag,
    u64* __restrict__ xbufW, int RW, int RE)
{
  const int tid  = threadIdx.x;
  const bool isX = (tid < 256);   // X: layer A of step t; Y: layer B of step t-1
  const int lane = tid & 63;
  const int qg   = (tid >> 6) & 3;  // wave within group
  const int w8   = tid >> 6;        // 0..7
  const int lo   = lane & 15;
  const int hi   = lane >> 4;
  const int blk  = blockIdx.x;
  const int P    = blk >> 3;      // layer pair 0..31
  const int g    = blk & 7;       // batch chunk (16 rows)
  const int LA   = 2 * P;
  const int NKCA = (P == 0) ? 4 : 2;
  u64* xbufE = (u64*)out_;        // encoder-phase ring lives in d_out

  extern __shared__ __align__(16) u16 dynlds[];   // weight tiles (120KB)

  __shared__ __align__(16) u16 hbA[2][16 * 72];
  __shared__ __align__(16) u16 hbB[2][16 * 72];
  __shared__ __align__(16) u16 xstA[2][16 * 72];
  __shared__ int s_cnt, s_fin, s_cn;
  if (tid == 0) { s_cnt = 0; s_fin = 0; s_cn = 0; }
  for (int i = tid; i < 16 * 72; i += 512) {
    hbA[0][i] = 0; hbA[1][i] = 0; hbB[0][i] = 0; hbB[1][i] = 0;
    xstA[0][i] = 0; xstA[1][i] = 0;
  }
  __syncthreads();
  {  // dtype probe: even u16s of enc_bih
    u16 v = ((const u16*)ebih_)[2 * (tid & 255)];
    int e = (v >> 7) & 0xFF;
    if (e >= 100 && e <= 126 && isX) atomicAdd(&s_cnt, 1);
  }
  __syncthreads();
  const bool bf = (s_cnt >= 128);   // true: bf16 tensors; false: fp32

  auto ld8 = [&](const void* p, int idx) -> short8 {
    if (bf) return *(const short8*)((const u16*)p + idx);
    const float* f = (const float*)p + idx;
    short8 r;
#pragma unroll
    for (int j = 0; j < 8; ++j) r[j] = (short)f2bf(f[j]);
    return r;
  };
  auto ld1 = [&](const void* p, int idx) -> float {
    return bf ? bf2f(((const u16*)p)[idx]) : ((const float*)p)[idx];
  };

  const int T0 = qg, T1 = 4 + qg, T2 = 8 + qg;

  short8 zf8 = {0,0,0,0,0,0,0,0};
  float  bov[2] = {0.f, 0.f};
  float brzA[2] = {0,0}, binA = 0, bhnA = 0;
  float brzB[2] = {0,0}, binB = 0, bhnB = 0;

  // ---- cooperative stage of a row-major (NT*16 x KC*32) matrix into LDS tiles
  auto stage_w = [&](int offU16, const void* W, int gidx0, int NT, int KC, int K) {
    for (int nt = w8; nt < NT; nt += 8)
      for (int kc = 0; kc < KC; ++kc) {
        short8 v = ld8(W, gidx0 + (nt*16 + lo)*K + kc*32 + hi*8);
        *(short8*)(dynlds + offU16 + (nt*KC + kc)*512 + lane*8) = v;
      }
  };

  auto load_phase = [&](int ph) {
    const void* WH  = ph ? dWhh_ : eWhh_;
    const void* WIs = ph ? dWih_ : eWih_;
    const void* WI0 = ph ? dWih0_ : eWih0_;
    const void* bi  = ph ? dbih_ : ebih_;
    const void* bh  = ph ? dbhh_ : ebhh_;
    stage_w(OFF_WHA, WH, LA*192*64, 12, 2, 64);
    stage_w(OFF_WHB, WH, (LA+1)*192*64, 12, 2, 64);
    stage_w(OFF_WIB, WIs, LA*192*64, 12, 2, 64);   // Wih[LB-1] = Wih[LA]
    if (LA == 0) stage_w(OFF_WIA, WI0, 0, 12, 4, 128);
    else         stage_w(OFF_WIA, WIs, (LA-1)*192*64, 12, 2, 64);
    if (isX) {
      brzA[0] = ld1(bi, LA*192 + T0*16 + lo) + ld1(bh, LA*192 + T0*16 + lo);
      brzA[1] = ld1(bi, LA*192 + T1*16 + lo) + ld1(bh, LA*192 + T1*16 + lo);
      binA    = ld1(bi, LA*192 + T2*16 + lo);
      bhnA    = ld1(bh, LA*192 + T2*16 + lo);
    } else {
      const int LB = LA + 1;
      brzB[0] = ld1(bi, LB*192 + T0*16 + lo) + ld1(bh, LB*192 + T0*16 + lo);
      brzB[1] = ld1(bi, LB*192 + T1*16 + lo) + ld1(bh, LB*192 + T1*16 + lo);
      binB    = ld1(bi, LB*192 + T2*16 + lo);
      bhnB    = ld1(bh, LB*192 + T2*16 + lo);
    }
  };
  load_phase(0);
  if (P == 31) {   // Wo staged once (OFF_WO untouched by load_phase(1): KCA=2)
    stage_w(OFF_WO, Wo_, 0, 8, 2, 64);
    if (!isX) { bov[0] = ld1(bo_, 32*qg + lo); bov[1] = ld1(bo_, 32*qg + 16 + lo); }
  }

  // ---- precomputed LDS u16 offsets for weight fragments
  const int oWhA0 = OFF_WHA + T0*1024 + lane*8;
  const int oWhA1 = OFF_WHA + T1*1024 + lane*8;
  const int oWhA2 = OFF_WHA + T2*1024 + lane*8;
  const int oWhB0 = OFF_WHB + T0*1024 + lane*8;
  const int oWhB1 = OFF_WHB + T1*1024 + lane*8;
  const int oWhB2 = OFF_WHB + T2*1024 + lane*8;
  const int oWiB0 = OFF_WIB + T0*1024 + lane*8;
  const int oWiB1 = OFF_WIB + T1*1024 + lane*8;
  const int oWiB2 = OFF_WIB + T2*1024 + lane*8;
  const int oWiA0 = OFF_WIA + T0*(NKCA*512) + lane*8;
  const int oWiA1 = OFF_WIA + T1*(NKCA*512) + lane*8;
  const int oWiA2 = OFF_WIA + T2*(NKCA*512) + lane*8;
  const int oWo0  = OFF_WO + (2*qg + 0)*1024 + lane*8;
  const int oWo1  = OFF_WO + (2*qg + 1)*1024 + lane*8;

  auto WF = [&](int off, int kc) -> short8 {   // one ds_read_b128, kc -> imm
    return *(const short8*)(dynlds + off + kc*512);
  };

  auto do_proj = [&](int tprev, const u16* hs) {   // Y-group only
    f32x4 pacc[2];
#pragma unroll
    for (int ct = 0; ct < 2; ++ct) { float v = bov[ct]; f32x4 tv = {v,v,v,v}; pacc[ct] = tv; }
#pragma unroll
    for (int kc = 0; kc < 2; ++kc) {
      short8 hA = *(const short8*)(hs + lo*72 + kc*32 + hi*8);
      pacc[0] = __builtin_amdgcn_mfma_f32_16x16x32_bf16(hA, WF(oWo0, kc), pacc[0], 0, 0, 0);
      pacc[1] = __builtin_amdgcn_mfma_f32_16x16x32_bf16(hA, WF(oWo1, kc), pacc[1], 0, 0, 0);
    }
#pragma unroll
    for (int ct = 0; ct < 2; ++ct) {
      int n = 32*qg + 16*ct + lo;
#pragma unroll
      for (int p = 0; p < 4; ++p) {
        int b = 16*g + hi*4 + p;
        size_t idx = ((size_t)b * 256 + (tprev - 256)) * 128 + n;
        float v = fminf(64.f, fmaxf(-64.f, pacc[ct][p]));
        if (bf) ((u16*)out_)[idx] = f2bf(v);
        else    ((float*)out_)[idx] = v;
      }
    }
  };

  float hprevA[4] = {0,0,0,0}, hprevB[4] = {0,0,0,0};
  const int brow = 16*g + lo;   // P0 context row

  const int eIn  = (P > 0 ? P - 1 : 0) * 8 + g;
  const int eOut = (P < 31 ? P : 30) * 8 + g;
  int* fin   = pflag + eIn  * FSTRIDE;
  int* fout  = pflag + eOut * FSTRIDE;
  int* cself = cflag + (P * 8 + g) * FSTRIDE;
  int* cnext = cflag + ((P < 31 ? P + 1 : 31) * 8 + g) * FSTRIDE;

  // ring address of record t (consumer side / producer side)
  auto raddr = [&](int t) -> const u64* {
    return (t < 256)
      ? (xbufE + (size_t)eIn * ((size_t)RE * 256) + (size_t)(t & (RE-1)) * 256)
      : (xbufW + (size_t)eIn * ((size_t)RW * 256) + (size_t)((t-256) & (RW-1)) * 256);
  };
  auto waddr = [&](int t) -> u64* {
    return (t < 256)
      ? (xbufE + (size_t)eOut * ((size_t)RE * 256) + (size_t)(t & (RE-1)) * 256)
      : (xbufW + (size_t)eOut * ((size_t)RW * 256) + (size_t)((t-256) & (RW-1)) * 256);
  };

  int budget = 1 << 22;   // anti-hang
  const int srow = 4 * (tid & 3);   // X record unpack: row quad
  const int scol = tid >> 2;        // X record unpack: h column (tid<256)

  int f0=0,f1=0,f2=0,f3=0, c0=0,c1=0,c2=0,c3=0;   // tid0 probe holds
  short8 cfx[4] = {zf8, zf8, zf8, zf8};           // P0 ctx prefetch (X)

  // ---- layer-B step (Y): compute B(s), write hbB[s&1], ring-store record(s)
  auto doB = [&](int s) {
    f32x4 br, bz, bin2, bhn;
    { float v;
      v = brzB[0]; br   = (f32x4){v,v,v,v};
      v = brzB[1]; bz   = (f32x4){v,v,v,v};
      v = binB;    bin2 = (f32x4){v,v,v,v};
      v = bhnB;    bhn  = (f32x4){v,v,v,v}; }
    const u16* hsB = hbB[(s + 1) & 1];   // h_B(s-1)
    const u16* xsB = hbA[s & 1];         // h_A(s)
#pragma unroll
    for (int kc = 0; kc < 2; ++kc) {
      short8 hB = *(const short8*)(hsB + lo*72 + kc*32 + hi*8);
      short8 xB = *(const short8*)(xsB + lo*72 + kc*32 + hi*8);
      br   = __builtin_amdgcn_mfma_f32_16x16x32_bf16(hB, WF(oWhB0, kc), br,   0, 0, 0);
      bz   = __builtin_amdgcn_mfma_f32_16x16x32_bf16(hB, WF(oWhB1, kc), bz,   0, 0, 0);
      bhn  = __builtin_amdgcn_mfma_f32_16x16x32_bf16(hB, WF(oWhB2, kc), bhn,  0, 0, 0);
      br   = __builtin_amdgcn_mfma_f32_16x16x32_bf16(xB, WF(oWiB0, kc), br,   0, 0, 0);
      bz   = __builtin_amdgcn_mfma_f32_16x16x32_bf16(xB, WF(oWiB1, kc), bz,   0, 0, 0);
      bin2 = __builtin_amdgcn_mfma_f32_16x16x32_bf16(xB, WF(oWiB2, kc), bin2, 0, 0, 0);
    }
    u16 hBb[4];
#pragma unroll
    for (int p = 0; p < 4; ++p) {
      float r = sigm(br[p]);
      float z = sigm(bz[p]);
      float n = tanhf_(bin2[p] + r * bhn[p]);
      float h = n + z * (hprevB[p] - n);
      h = fminf(1.f, fmaxf(-1.f, h));
      hprevB[p] = h;
      hBb[p] = f2bf(h);
    }
    u16* hd = hbB[s & 1];
#pragma unroll
    for (int p = 0; p < 4; ++p)
      hd[(hi*4 + p) * 72 + qg*16 + lo] = hBb[p];
    if (P < 31) {
      u64 da = (u64)hBb[0] | ((u64)hBb[1] << 16) | ((u64)hBb[2] << 32) | ((u64)hBb[3] << 48);
      FST(waddr(s) + (16*qg + lo)*4 + hi, da);
    }
  };

  __syncthreads();   // weight tiles + buffers visible

  // ---------------- span: slots t = tbase..tbase+255 (X:A(t), Y:B(t-1)) + tail
  auto span = [&](auto chc, const int tbase, const int cbase, const int RC, const bool dec) {
    constexpr int CH  = decltype(chc)::value;
    constexpr int PTT = (CH >= 2) ? CH - 2 : 0;
    const int NC = 256 / CH;

    // ---- prologue: wait + stage x(tbase); P0: ctx prefetch for tbase
    if (P > 0) {
      if (tid == 0) {
        int v = s_fin;
        if (v < cbase + 1) {
          while (budget > 0) {
            int a = FLD(fin+0), b = FLD(fin+1), c = FLD(fin+2), d = FLD(fin+3);
            v = imin(imin(a, b), imin(c, d));
            if (v >= cbase + 1) break;
            --budget; __builtin_amdgcn_s_sleep(2);
          }
          s_fin = v;
        }
      }
      __syncthreads();
      if (isX) {
        u64 r0 = FLD(raddr(tbase) + tid);
        u16* xd = xstA[tbase & 1];
#pragma unroll
        for (int p = 0; p < 4; ++p) xd[(srow + p) * 72 + scol] = (u16)(r0 >> (16 * p));
      }
    }
    if (P == 0 && isX) {
      int tx = (tbase < 256) ? tbase : 0;
#pragma unroll
      for (int kc = 0; kc < 4; ++kc) cfx[kc] = ld8(ctx_, (brow*256 + tx)*128 + kc*32 + hi*8);
    }

#pragma unroll 1
    for (int k = 0; k < NC; ++k) {
      const int t0 = tbase + k * CH;
      const int ck = cbase + k;
      const int fneed = ck + 2 - ((dec && k == NC - 1) ? 1 : 0);
      const int need  = (k >= RC) ? (ck + 1 - RC) : 0;
      u64 ra[CH];
#pragma unroll
      for (int j = 0; j < CH; ++j) ra[j] = 0;

#pragma unroll
      for (int tt = 0; tt < CH; ++tt) {
        const int t = t0 + tt;
        lds_barrier();   // slot start: all slot t-1 writes visible

        if (tt == 0) {
          int vf = s_fin, vc = s_cn;
          const bool slowF = (P > 0)  && (vf < fneed);
          const bool slowC = (P < 31) && (need > 0) && (vc < need);
          if (slowF || slowC) {
            if (tid == 0) {
              if (slowF) {
                int v = 0;
                while (budget > 0) {
                  int a = FLD(fin+0), b = FLD(fin+1), c = FLD(fin+2), d = FLD(fin+3);
                  v = imin(imin(a, b), imin(c, d));
                  if (v >= fneed) break;
                  --budget; __builtin_amdgcn_s_sleep(2);
                }
                s_fin = v;
              }
              if (slowC) {
                int v = 0;
                while (budget > 0) {
                  int a = FLD(cnext+0), b = FLD(cnext+1), c = FLD(cnext+2), d = FLD(cnext+3);
                  v = imin(imin(a, b), imin(c, d));
                  if (v >= need) break;
                  --budget; __builtin_amdgcn_s_sleep(2);
                }
                s_cn = v;
              }
            }
            lds_barrier();
          }
          if (isX && P > 0) {   // prime records t0+1..t0+CH
#pragma unroll
            for (int j = 0; j < CH; ++j)
              if (t0 + 1 + j <= 511) ra[j] = FLD(raddr(t0 + 1 + j) + tid);
          }
        }

        if (isX) {
          // publish old probes (pre-issue ordering safe for CH==1)
          if (tt == CH - 1 && tid == 0) {
            if (P > 0)  s_fin = imin(imin(f0, f1), imin(f2, f3));
            if (P < 31) s_cn  = imin(imin(c0, c1), imin(c2, c3));
          }
          if (tt == PTT && tid == 0) {
            if (P > 0)  { f0 = FLD(fin+0); f1 = FLD(fin+1); f2 = FLD(fin+2); f3 = FLD(fin+3); }
            if (P < 31) { c0 = FLD(cnext+0); c1 = FLD(cnext+1); c2 = FLD(cnext+2); c3 = FLD(cnext+3); }
          }

          // ================= layer A(t) =================
          f32x4 ar, az, ain, ahn;
          { float v;
            v = brzA[0]; ar  = (f32x4){v,v,v,v};
            v = brzA[1]; az  = (f32x4){v,v,v,v};
            v = binA;    ain = (f32x4){v,v,v,v};
            v = bhnA;    ahn = (f32x4){v,v,v,v}; }
          const u16* hsA = hbA[(t + 1) & 1];
#pragma unroll
          for (int kc = 0; kc < 2; ++kc) {
            short8 hA = *(const short8*)(hsA + lo*72 + kc*32 + hi*8);
            ar  = __builtin_amdgcn_mfma_f32_16x16x32_bf16(hA, WF(oWhA0, kc), ar,  0, 0, 0);
            az  = __builtin_amdgcn_mfma_f32_16x16x32_bf16(hA, WF(oWhA1, kc), az,  0, 0, 0);
            ahn = __builtin_amdgcn_mfma_f32_16x16x32_bf16(hA, WF(oWhA2, kc), ahn, 0, 0, 0);
          }
          short8 xfA[4] = {zf8, zf8, zf8, zf8};
          if (P > 0) {
            const u16* xs = xstA[t & 1];
#pragma unroll
            for (int kc = 0; kc < 2; ++kc)
              xfA[kc] = *(const short8*)(xs + lo*72 + kc*32 + hi*8);
          } else {
#pragma unroll
            for (int kc = 0; kc < 4; ++kc) xfA[kc] = cfx[kc];
          }
          if (!(P == 0 && t == 256)) {
#pragma unroll
            for (int kc = 0; kc < 4; ++kc) {
              if (kc < NKCA) {
                ar  = __builtin_amdgcn_mfma_f32_16x16x32_bf16(xfA[kc], WF(oWiA0, kc), ar,  0, 0, 0);
                az  = __builtin_amdgcn_mfma_f32_16x16x32_bf16(xfA[kc], WF(oWiA1, kc), az,  0, 0, 0);
                ain = __builtin_amdgcn_mfma_f32_16x16x32_bf16(xfA[kc], WF(oWiA2, kc), ain, 0, 0, 0);
              }
            }
          }
          u16 hAb[4];
#pragma unroll
          for (int p = 0; p < 4; ++p) {
            float r = sigm(ar[p]);
            float z = sigm(az[p]);
            float n = tanhf_(ain[p] + r * ahn[p]);
            float h = n + z * (hprevA[p] - n);
            h = fminf(1.f, fmaxf(-1.f, h));
            hprevA[p] = h;
            hAb[p] = f2bf(h);
          }
          {
            u16* hd = hbA[t & 1];
#pragma unroll
            for (int p = 0; p < 4; ++p)
              hd[(hi*4 + p) * 72 + qg*16 + lo] = hAb[p];
          }
          if (P == 0) {              // prefetch ctx for t+1
            int tn = t + 1;
            if (tn <= 511) {
              int tx = (tn < 256) ? tn : ((tn == 256) ? 0 : tn - 257);
#pragma unroll
              for (int kc = 0; kc < 4; ++kc)
                cfx[kc] = ld8(ctx_, (brow*256 + tx)*128 + kc*32 + hi*8);
            }
          }
          if (P > 0 && t < 511) {    // stage x(t+1) -> xstA[(t+1)&1]
            u64 r = ra[tt];
            u16* xd = xstA[(t + 1) & 1];
#pragma unroll
            for (int p = 0; p < 4; ++p) xd[(srow + p) * 72 + scol] = (u16)(r >> (16 * p));
          }
          if (tt == CH - 1 && P > 0) {   // consumer credit (per X wave)
            DRAIN0();
            if (lane == 0) FST(cself + qg, ck + 1);
          }
        } else {
          // ================= Y: proj + B(t-1) + flags =================
          if (P == 31 && dec && t >= 258) do_proj(t - 2, hbB[t & 1]);
          if (t - 1 >= tbase) doB(t - 1);
          if (P < 31 && tt == 0 && k > 0) {   // flag for chunk ck-1 (records <= t0-1)
            DRAIN0();
            if (lane == 0) FST(fout + qg, ck);
          }
        }
      }
    }

    // ---- tail slot: Y computes B(tbase+255)
    lds_barrier();
    if (!isX) {
      doB(tbase + 255);
      if (P < 31) {
        DRAIN0();
        if (lane == 0) FST(fout + qg, cbase + NC);   // all span chunks complete
      }
    }
  };

  span(IC<CHE>{}, 0, 0, RE / CHE, false);          // encoder (ring in d_out)
  __syncthreads();
  load_phase(1);                                   // decoder weights -> LDS
  __syncthreads();
  {
    int rcd = RW / CHD; if (rcd < 1) rcd = 1;
    span(IC<CHD>{}, 256, 256 / CHE, rcd, true);    // decoder (ring in ws)
  }

  // ---- epilogue: projections of steps 510, 511
  lds_barrier();
  if (P == 31 && !isX) {
    do_proj(510, hbB[0]);
    do_proj(511, hbB[1]);
  }
}

extern "C" void kernel_launch(void* const* d_in, const int* in_sizes, int n_in,
                              void* d_out, int out_size, void* d_ws, size_t ws_size,
                              hipStream_t stream)
{
  char* ws = (char*)d_ws;
  int* pflag = (int*)ws;                    // 248 edges x 64B per-wave flag lines
  int* cflag = (int*)(ws + 16384);          // 256 x 64B per-wave credit lines
  u64* xbufW = (u64*)(ws + 32768);          // decoder-phase handoff ring

  const size_t per_slot = (size_t)31 * 8 * 2048;  // one ring step across all 31x8 edges
  size_t avail = (ws_size > 32768) ? ws_size - 32768 : 0;
  int RW = 1;
  for (int r = 128; r >= 1; r >>= 1)
    if ((size_t)r * per_slot <= avail) { RW = r; break; }
  // encoder-phase ring borrows d_out (dead until pair31's first projection)
  int RE = 1;
  for (int r = 16; r >= 1; r >>= 1)
    if ((size_t)r * per_slot <= (size_t)out_size) { RE = r; break; }

  const int dyn = 122880;   // 120KB weight tiles in dynamic LDS
  static int attr_done = 0;
  if (!attr_done) {
    hipFuncSetAttribute(reinterpret_cast<const void*>(gru_pipeline<2,4>),
                        hipFuncAttributeMaxDynamicSharedMemorySize, dyn);
    hipFuncSetAttribute(reinterpret_cast<const void*>(gru_pipeline<2,2>),
                        hipFuncAttributeMaxDynamicSharedMemorySize, dyn);
    hipFuncSetAttribute(reinterpret_cast<const void*>(gru_pipeline<2,1>),
                        hipFuncAttributeMaxDynamicSharedMemorySize, dyn);
    attr_done = 1;
  }

  hipMemsetAsync(ws, 0, 32768, stream);     // zero flags every launch

#define LAUNCH(CE, CD)                                                     \
  gru_pipeline<CE, CD><<<256, 512, dyn, stream>>>(                         \
      d_in[0], d_in[1], d_in[2], d_in[3], d_in[4], d_in[5],                \
      d_in[6], d_in[7], d_in[8], d_in[9], d_in[10], d_in[11], d_in[12],    \
      d_out, pflag, cflag, xbufW, RW, RE)

  if      (RW >= 16) LAUNCH(2, 4);
  else if (RW >= 8)  LAUNCH(2, 2);
  else               LAUNCH(2, 1);
#undef LAUNCH
  (void)in_sizes; (void)n_in;
}